// Round 1
// baseline (288.266 us; speedup 1.0000x reference)
//
#include <hip/hip_runtime.h>
#include <math.h>

namespace {
constexpr int kB = 256;
constexpr int kT = 64;
constexpr int kPhys = 3;
constexpr int kLat = 8;
constexpr int kNN = 128;
constexpr int kNHid = 3;
constexpr int kWin = 32;
constexpr int kPred = 64;
constexpr int kR = 33;          // kT - kWin + 1
constexpr int kHPad = kNN + 4;  // 132 floats: float4-aligned rows, 2-way-free LDS banks
}

// -------------------- MLP (f32, VALU) --------------------
// One block per batch element (64 rows). 256 threads.
// Hidden layers: 8 row-groups x 32 neuron-quads, acc[8][4] in registers,
// float4 LDS reads of activations (broadcast), float4 coalesced weight loads.
template<int IN_DIM, int OUT_DIM>
__global__ __launch_bounds__(256) void mlp_kernel(
    const float* __restrict__ in,
    const float* __restrict__ w_in, const float* __restrict__ b_in,
    const float* __restrict__ w_h,  const float* __restrict__ b_h,
    const float* __restrict__ w_out,const float* __restrict__ b_out,
    float* __restrict__ out)
{
  __shared__ float hb[kT][kHPad];
  __shared__ float inb[kT][IN_DIM];
  const int tid = threadIdx.x;
  const int b = blockIdx.x;
  const float* __restrict__ inrow = in + (size_t)b * kT * IN_DIM;

  for (int i = tid; i < kT * IN_DIM; i += 256) inb[i / IN_DIM][i % IN_DIM] = inrow[i];
  __syncthreads();

  // input layer: IN_DIM -> 128, relu
  {
    const int j = tid & (kNN - 1);
    const int rh = tid >> 7;  // 0/1, wave-uniform
    float wr[IN_DIM];
#pragma unroll
    for (int k = 0; k < IN_DIM; ++k) wr[k] = w_in[k * kNN + j];
    const float bj = b_in[j];
    for (int c = 0; c < kT / 2; ++c) {
      const int r = 2 * c + rh;
      float acc = bj;
#pragma unroll
      for (int k = 0; k < IN_DIM; ++k) acc += inb[r][k] * wr[k];
      hb[r][j] = fmaxf(acc, 0.f);
    }
  }
  __syncthreads();

  // hidden layers: 128 -> 128, relu (in-place ping via barrier)
  const int g = tid >> 5;          // row group: rows 8g..8g+7
  const int jb = (tid & 31) * 4;   // neuron quad base
  for (int L = 0; L < kNHid; ++L) {
    const float* __restrict__ W = w_h + (size_t)L * kNN * kNN;
    float acc[8][4];
#pragma unroll
    for (int r = 0; r < 8; ++r) { acc[r][0] = 0.f; acc[r][1] = 0.f; acc[r][2] = 0.f; acc[r][3] = 0.f; }
    for (int k4 = 0; k4 < kNN; k4 += 4) {
      const float4 w0 = *(const float4*)&W[(k4 + 0) * kNN + jb];
      const float4 w1 = *(const float4*)&W[(k4 + 1) * kNN + jb];
      const float4 w2 = *(const float4*)&W[(k4 + 2) * kNN + jb];
      const float4 w3 = *(const float4*)&W[(k4 + 3) * kNN + jb];
#pragma unroll
      for (int r = 0; r < 8; ++r) {
        const float4 hv = *(const float4*)&hb[g * 8 + r][k4];
        acc[r][0] += hv.x * w0.x + hv.y * w1.x + hv.z * w2.x + hv.w * w3.x;
        acc[r][1] += hv.x * w0.y + hv.y * w1.y + hv.z * w2.y + hv.w * w3.y;
        acc[r][2] += hv.x * w0.z + hv.y * w1.z + hv.z * w2.z + hv.w * w3.z;
        acc[r][3] += hv.x * w0.w + hv.y * w1.w + hv.z * w2.w + hv.w * w3.w;
      }
    }
    const float* __restrict__ bh = b_h + L * kNN;
    const float bb0 = bh[jb + 0], bb1 = bh[jb + 1], bb2 = bh[jb + 2], bb3 = bh[jb + 3];
    __syncthreads();  // all reads of hb done before any in-place overwrite
#pragma unroll
    for (int r = 0; r < 8; ++r) {
      float4 o;
      o.x = fmaxf(acc[r][0] + bb0, 0.f);
      o.y = fmaxf(acc[r][1] + bb1, 0.f);
      o.z = fmaxf(acc[r][2] + bb2, 0.f);
      o.w = fmaxf(acc[r][3] + bb3, 0.f);
      *(float4*)&hb[g * 8 + r][jb] = o;
    }
    __syncthreads();
  }

  // output layer: 128 -> OUT_DIM (no relu)
  for (int idx = tid; idx < kT * OUT_DIM; idx += 256) {
    const int r = idx / OUT_DIM;
    const int o = idx - r * OUT_DIM;
    float acc = b_out[o];
    for (int k = 0; k < kNN; k += 4) {
      const float4 hv = *(const float4*)&hb[r][k];
      acc += hv.x * w_out[(k + 0) * OUT_DIM + o];
      acc += hv.y * w_out[(k + 1) * OUT_DIM + o];
      acc += hv.z * w_out[(k + 2) * OUT_DIM + o];
      acc += hv.w * w_out[(k + 3) * OUT_DIM + o];
    }
    out[((size_t)b * kT + r) * OUT_DIM + o] = acc;
  }
}

// -------------------- Hankel-DMD (exact-math rewrite, f64) --------------------
// recon[b,p,l] = (A^p Ym[:,0])[l*R]; for p<=31 this is exactly y[b,p,l].
// For p>=32: z_{32+k} = Yp K^k c0, K = G^{-1}(Ym^T Yp), c0 = K[:,30],
// with everything derived from Corr[a][c] = sum_{l,r<33} y[l,r+a]*y[l,r+c].
__global__ __launch_bounds__(256) void dmd_kernel(const float* __restrict__ y,
                                                  float* __restrict__ yadv)
{
  __shared__ double yd[kLat][kT];       // y (transposed) in f64
  __shared__ double Corr[kR][kR + 1];   // 33x34
  __shared__ double Lm[31][33];         // Cholesky factor (lower), padded
  __shared__ double Km[31][33];         // K = G^{-1} Ym^T Yp
  __shared__ double Zb[31][33];         // forward-solve temp
  __shared__ double Dv[32][33];         // d_k = K^k c0
  __shared__ double invd[31];
  const int tid = threadIdx.x;
  const int b = blockIdx.x;
  const float* __restrict__ yb = y + (size_t)b * kT * kLat;
  float* __restrict__ ob = yadv + (size_t)b * kPred * kLat;

  for (int i = tid; i < kT * kLat; i += 256) {
    const int t = i >> 3, l = i & 7;
    yd[l][t] = (double)yb[i];
  }
  __syncthreads();

  // correlation table
  for (int idx = tid; idx < kR * kR; idx += 256) {
    const int a = idx / kR, c = idx - a * kR;
    double s = 0.0;
#pragma unroll
    for (int l = 0; l < kLat; ++l) {
      const double* __restrict__ ya = &yd[l][a];
      const double* __restrict__ yc = &yd[l][c];
      for (int r = 0; r < kR; ++r) s += ya[r] * yc[r];
    }
    Corr[a][c] = s;
  }
  __syncthreads();

  // G = Corr[0:31,0:31] -> Lm (lower triangle copy)
  for (int idx = tid; idx < 31 * 31; idx += 256) {
    const int i = idx / 31, j = idx - i * 31;
    Lm[i][j] = Corr[i][j];
  }
  __syncthreads();

  // Cholesky (right-looking, lane-per-row)
  for (int j = 0; j < 31; ++j) {
    if (tid == 0) {
      const double d = sqrt(Lm[j][j]);
      Lm[j][j] = d;
      invd[j] = 1.0 / d;
    }
    __syncthreads();
    if (tid > j && tid < 31) Lm[tid][j] *= invd[j];
    __syncthreads();
    if (tid > j && tid < 31) {
      const double lij = Lm[tid][j];
      for (int k = j + 1; k <= tid; ++k) Lm[tid][k] -= lij * Lm[k][j];
    }
    __syncthreads();
  }

  // Solve G K = Ym^T Yp  (31 rhs columns; rhs col c = Corr[:, c+1]).
  // Lanes are independent columns: no barriers needed inside.
  if (tid < 31) {
    const int c = tid;
    for (int i = 0; i < 31; ++i) {
      double s = Corr[i][c + 1];
      for (int k = 0; k < i; ++k) s -= Lm[i][k] * Zb[k][c];
      Zb[i][c] = s * invd[i];
    }
    for (int i = 30; i >= 0; --i) {
      double s = Zb[i][c];
      for (int k = i + 1; k < 31; ++k) s -= Lm[k][i] * Km[k][c];
      Km[i][c] = s * invd[i];
    }
  }
  __syncthreads();

  // power iteration: d_0 = c0 = K[:,30]; d_{k+1} = K d_k
  if (tid < 31) Dv[0][tid] = Km[tid][30];
  __syncthreads();
  for (int k = 0; k < 31; ++k) {
    if (tid < 31) {
      double s = 0.0;
      for (int j = 0; j < 31; ++j) s += Km[tid][j] * Dv[k][j];
      Dv[k + 1][tid] = s;
    }
    __syncthreads();
  }

  // p < 32: exact copy of y (same (t,l) layout)
  for (int i = tid; i < kWin * kLat; i += 256) ob[i] = yb[i];
  // p >= 32: y_adv[b,32+k,l] = sum_j y[l][j+1] * d_k[j]
  for (int idx = tid; idx < (kPred - kWin) * kLat; idx += 256) {
    const int k = idx >> 3, l = idx & 7;
    double s = 0.0;
    for (int j = 0; j < 31; ++j) s += yd[l][j + 1] * Dv[k][j];
    ob[(kWin + k) * kLat + l] = (float)s;
  }
}

extern "C" void kernel_launch(void* const* d_in, const int* in_sizes, int n_in,
                              void* d_out, int out_size, void* d_ws, size_t ws_size,
                              hipStream_t stream)
{
  const float* x         = (const float*)d_in[0];
  const float* enc_w_in  = (const float*)d_in[1];
  const float* enc_b_in  = (const float*)d_in[2];
  const float* enc_w_h   = (const float*)d_in[3];
  const float* enc_b_h   = (const float*)d_in[4];
  const float* enc_w_out = (const float*)d_in[5];
  const float* enc_b_out = (const float*)d_in[6];
  const float* dec_w_in  = (const float*)d_in[7];
  const float* dec_b_in  = (const float*)d_in[8];
  const float* dec_w_h   = (const float*)d_in[9];
  const float* dec_b_h   = (const float*)d_in[10];
  const float* dec_w_out = (const float*)d_in[11];
  const float* dec_b_out = (const float*)d_in[12];

  float* out   = (float*)d_out;
  float* y     = out;                                  // (B,T,8)   131072
  float* x_ae  = out + (size_t)kB * kT * kLat;         // (B,T,3)    49152
  float* x_adv = x_ae + (size_t)kB * kT * kPhys;       // (B,T,3)    49152
  float* y_adv = x_adv + (size_t)kB * kT * kPhys;      // (B,64,8)  131072

  mlp_kernel<kPhys, kLat><<<kB, 256, 0, stream>>>(
      x, enc_w_in, enc_b_in, enc_w_h, enc_b_h, enc_w_out, enc_b_out, y);
  dmd_kernel<<<kB, 256, 0, stream>>>(y, y_adv);
  mlp_kernel<kLat, kPhys><<<kB, 256, 0, stream>>>(
      y, dec_w_in, dec_b_in, dec_w_h, dec_b_h, dec_w_out, dec_b_out, x_ae);
  mlp_kernel<kLat, kPhys><<<kB, 256, 0, stream>>>(
      y_adv, dec_w_in, dec_b_in, dec_w_h, dec_b_h, dec_w_out, dec_b_out, x_adv);
}

// Round 2
// 118.614 us; speedup vs baseline: 2.4303x; 2.4303x over previous
//
#include <hip/hip_runtime.h>
#include <math.h>

namespace {
constexpr int kB = 256;
constexpr int kT = 64;
constexpr int kPhys = 3;
constexpr int kLat = 8;
constexpr int kNN = 128;
constexpr int kNHid = 3;
constexpr int kWin = 32;
constexpr int kPred = 64;
constexpr int kHPad = kNN + 4;  // float4-aligned rows
}

__device__ __forceinline__ double rdlane_f64(double x, int l) {
  const long long v = __double_as_longlong(x);
  const int lo = __builtin_amdgcn_readlane((int)(unsigned int)(v & 0xffffffffll), l);
  const int hi = __builtin_amdgcn_readlane((int)(v >> 32), l);
  const long long r = (((long long)hi) << 32) | (unsigned long long)(unsigned int)lo;
  return __longlong_as_double(r);
}

// -------------------- MLP (f32, VALU), 512 threads --------------------
// Dual-source: blocks [0,256) use in0/out0, [256,512) use in1/out1.
template<int IN_DIM, int OUT_DIM>
__global__ __launch_bounds__(512) void mlp_kernel(
    const float* __restrict__ in0, const float* __restrict__ in1,
    const float* __restrict__ w_in, const float* __restrict__ b_in,
    const float* __restrict__ w_h,  const float* __restrict__ b_h,
    const float* __restrict__ w_out,const float* __restrict__ b_out,
    float* __restrict__ out0, float* __restrict__ out1)
{
  __shared__ float hb[kT][kHPad];
  __shared__ float inb[kT][IN_DIM];
  const int tid = threadIdx.x;
  const int bb = blockIdx.x;
  const int b = bb & (kB - 1);
  const float* __restrict__ inp = (bb < kB ? in0 : in1) + (size_t)b * kT * IN_DIM;
  float* __restrict__ outp = (bb < kB ? out0 : out1) + (size_t)b * kT * OUT_DIM;

  for (int i = tid; i < kT * IN_DIM; i += 512) inb[i / IN_DIM][i % IN_DIM] = inp[i];
  __syncthreads();

  // input layer: IN_DIM -> 128, relu
  {
    const int j = tid & (kNN - 1);
    const int rh = tid >> 7;  // 0..3
    float wr[IN_DIM];
#pragma unroll
    for (int k = 0; k < IN_DIM; ++k) wr[k] = w_in[k * kNN + j];
    const float bj = b_in[j];
#pragma unroll
    for (int c = 0; c < kT / 4; ++c) {
      const int r = 4 * c + rh;
      float acc = bj;
#pragma unroll
      for (int k = 0; k < IN_DIM; ++k) acc += inb[r][k] * wr[k];
      hb[r][j] = fmaxf(acc, 0.f);
    }
  }
  __syncthreads();

  // hidden layers: 128 -> 128, relu
  const int g = tid >> 5;          // 0..15, rows 4g..4g+3
  const int jb = (tid & 31) * 4;   // neuron quad base
  for (int L = 0; L < kNHid; ++L) {
    const float* __restrict__ W = w_h + (size_t)L * kNN * kNN;
    float acc[4][4];
#pragma unroll
    for (int r = 0; r < 4; ++r) { acc[r][0] = 0.f; acc[r][1] = 0.f; acc[r][2] = 0.f; acc[r][3] = 0.f; }
    for (int k4 = 0; k4 < kNN; k4 += 4) {
      const float4 w0 = *(const float4*)&W[(k4 + 0) * kNN + jb];
      const float4 w1 = *(const float4*)&W[(k4 + 1) * kNN + jb];
      const float4 w2 = *(const float4*)&W[(k4 + 2) * kNN + jb];
      const float4 w3 = *(const float4*)&W[(k4 + 3) * kNN + jb];
#pragma unroll
      for (int r = 0; r < 4; ++r) {
        const float4 hv = *(const float4*)&hb[g * 4 + r][k4];
        acc[r][0] += hv.x * w0.x + hv.y * w1.x + hv.z * w2.x + hv.w * w3.x;
        acc[r][1] += hv.x * w0.y + hv.y * w1.y + hv.z * w2.y + hv.w * w3.y;
        acc[r][2] += hv.x * w0.z + hv.y * w1.z + hv.z * w2.z + hv.w * w3.z;
        acc[r][3] += hv.x * w0.w + hv.y * w1.w + hv.z * w2.w + hv.w * w3.w;
      }
    }
    const float* __restrict__ bh = b_h + L * kNN;
    const float bb0 = bh[jb + 0], bb1 = bh[jb + 1], bb2 = bh[jb + 2], bb3 = bh[jb + 3];
    __syncthreads();
#pragma unroll
    for (int r = 0; r < 4; ++r) {
      float4 o;
      o.x = fmaxf(acc[r][0] + bb0, 0.f);
      o.y = fmaxf(acc[r][1] + bb1, 0.f);
      o.z = fmaxf(acc[r][2] + bb2, 0.f);
      o.w = fmaxf(acc[r][3] + bb3, 0.f);
      *(float4*)&hb[g * 4 + r][jb] = o;
    }
    __syncthreads();
  }

  // output layer: 128 -> OUT_DIM
  for (int idx = tid; idx < kT * OUT_DIM; idx += 512) {
    const int r = idx / OUT_DIM;
    const int o = idx - r * OUT_DIM;
    float acc = b_out[o];
    for (int k = 0; k < kNN; k += 4) {
      const float4 hv = *(const float4*)&hb[r][k];
      acc += hv.x * w_out[(k + 0) * OUT_DIM + o];
      acc += hv.y * w_out[(k + 1) * OUT_DIM + o];
      acc += hv.z * w_out[(k + 2) * OUT_DIM + o];
      acc += hv.w * w_out[(k + 3) * OUT_DIM + o];
    }
    outp[(size_t)r * OUT_DIM + o] = acc;
  }
}

// -------------------- Hankel-DMD --------------------
// y_adv[p<32] = y[p].  For p=32+k: y_adv[32+k,l] = sum_j y[l][j+1] d_k[j],
// d_0 = G^-1 Corr[:,31], d_{k+1} = K d_k, K = G^-1 C, C[a][c]=Corr[a][c+1],
// G = Corr[0:31,0:31], Corr[a][c] = sum_{l,r<33} y[l][r+a] y[l][r+c].
__global__ __launch_bounds__(256) void dmd_kernel(const float* __restrict__ y,
                                                  float* __restrict__ yadv)
{
  __shared__ double yd[kLat][kT + 1];   // [8][65]
  __shared__ double P[32][67];          // lag products, padded
  __shared__ double Corr[32][33];       // padded
  __shared__ double KT[31][33];         // K transpose staging
  __shared__ double Dv[32][33];         // d_k vectors
  const int tid = threadIdx.x;
  const int b = blockIdx.x;
  const float* __restrict__ yb = y + (size_t)b * kT * kLat;
  float* __restrict__ ob = yadv + (size_t)b * kPred * kLat;

  for (int i = tid; i < kT * kLat; i += 256) {
    const int t = i >> 3, l = i & 7;
    yd[l][t] = (double)yb[i];
  }
  __syncthreads();

  // P[d][t] = sum_l yd[l][t] * yd[l][t+d]   (t+d < 64)
  for (int idx = tid; idx < 32 * 64; idx += 256) {
    const int d = idx >> 6, t = idx & 63;
    if (t + d < kT) {
      double s = 0.0;
#pragma unroll
      for (int l = 0; l < kLat; ++l) s += yd[l][t] * yd[l][t + d];
      P[d][t] = s;
    }
  }
  __syncthreads();

  // Corr[a][c] = sum_{r=0..32} P[|c-a|][min(a,c)+r],  a,c in [0,32)
  for (int idx = tid; idx < 32 * 32; idx += 256) {
    const int a = idx >> 5, c = idx & 31;
    const int d = (c >= a) ? (c - a) : (a - c);
    const int base = (c >= a) ? a : c;
    double s0 = 0.0, s1 = 0.0;
#pragma unroll
    for (int r = 0; r < 32; r += 2) { s0 += P[d][base + r]; s1 += P[d][base + r + 1]; }
    Corr[a][c] = s0 + s1 + P[d][base + 32];
  }
  __syncthreads();

  // ---- single-wave register algebra ----
  if (tid < 64) {
    const int lane = tid;
    // augmented [G | C] column-per-lane: lanes 0..30 = G cols, 31..61 = C cols
    const int colidx = (lane <= 30) ? lane : (lane <= 61 ? lane - 30 : 1);
    double m[31];
#pragma unroll
    for (int i = 0; i < 31; ++i) m[i] = Corr[i][colidx];

    // Gauss-Jordan [G|C] -> [I|K] (no pivoting; G is SPD well-conditioned)
#pragma unroll
    for (int k = 0; k < 31; ++k) {
      const double piv = rdlane_f64(m[k], k);
      const double pinv = 1.0 / piv;
      m[k] *= pinv;
#pragma unroll
      for (int i = 0; i < 31; ++i) {
        if (i == k) continue;
        const double bci = rdlane_f64(m[i], k);
        m[i] = fma(-bci, m[k], m[i]);
      }
    }

    // stage K columns to LDS, re-read as rows (lane i holds K[i][:])
    if (lane >= 31 && lane < 62) {
      const int c = lane - 31;
#pragma unroll
      for (int i = 0; i < 31; ++i) KT[i][c] = m[i];
    }
    const int ri = (lane < 31) ? lane : 0;
    double Kr[31];
#pragma unroll
    for (int j = 0; j < 31; ++j) Kr[j] = KT[ri][j];

    // power iteration in registers: d_{k+1} = K d_k, broadcast via readlane
    double dv = Kr[30];  // d_0 = K[:,30]
    if (lane < 31) Dv[0][lane] = dv;
    for (int k = 0; k < 31; ++k) {
      double acc[4] = {0.0, 0.0, 0.0, 0.0};
#pragma unroll
      for (int j = 0; j < 31; ++j) {
        const double dj = rdlane_f64(dv, j);
        acc[j & 3] = fma(Kr[j], dj, acc[j & 3]);
      }
      dv = (acc[0] + acc[1]) + (acc[2] + acc[3]);
      if (lane < 31) Dv[k + 1][lane] = dv;
    }
  }
  __syncthreads();

  // p < 32: exact copy of y
  for (int i = tid; i < kWin * kLat; i += 256) ob[i] = yb[i];
  // p >= 32: y_adv[32+k, l] = sum_j y[l][j+1] * d_k[j]
  {
    const int k = tid >> 3, l = tid & 7;  // 256 threads = 32*8 exactly
    double acc[4] = {0.0, 0.0, 0.0, 0.0};
#pragma unroll
    for (int j = 0; j < 31; ++j) acc[j & 3] = fma(yd[l][j + 1], Dv[k][j], acc[j & 3]);
    ob[(kWin + k) * kLat + l] = (float)((acc[0] + acc[1]) + (acc[2] + acc[3]));
  }
}

extern "C" void kernel_launch(void* const* d_in, const int* in_sizes, int n_in,
                              void* d_out, int out_size, void* d_ws, size_t ws_size,
                              hipStream_t stream)
{
  const float* x         = (const float*)d_in[0];
  const float* enc_w_in  = (const float*)d_in[1];
  const float* enc_b_in  = (const float*)d_in[2];
  const float* enc_w_h   = (const float*)d_in[3];
  const float* enc_b_h   = (const float*)d_in[4];
  const float* enc_w_out = (const float*)d_in[5];
  const float* enc_b_out = (const float*)d_in[6];
  const float* dec_w_in  = (const float*)d_in[7];
  const float* dec_b_in  = (const float*)d_in[8];
  const float* dec_w_h   = (const float*)d_in[9];
  const float* dec_b_h   = (const float*)d_in[10];
  const float* dec_w_out = (const float*)d_in[11];
  const float* dec_b_out = (const float*)d_in[12];

  float* out   = (float*)d_out;
  float* y     = out;                                  // (B,T,8)   131072
  float* x_ae  = out + (size_t)kB * kT * kLat;         // (B,T,3)    49152
  float* x_adv = x_ae + (size_t)kB * kT * kPhys;       // (B,T,3)    49152
  float* y_adv = x_adv + (size_t)kB * kT * kPhys;      // (B,64,8)  131072

  mlp_kernel<kPhys, kLat><<<kB, 512, 0, stream>>>(
      x, nullptr, enc_w_in, enc_b_in, enc_w_h, enc_b_h, enc_w_out, enc_b_out, y, nullptr);
  dmd_kernel<<<kB, 256, 0, stream>>>(y, y_adv);
  mlp_kernel<kLat, kPhys><<<2 * kB, 512, 0, stream>>>(
      y, y_adv, dec_w_in, dec_b_in, dec_w_h, dec_b_h, dec_w_out, dec_b_out, x_ae, x_adv);
}

// Round 3
// 99.510 us; speedup vs baseline: 2.8969x; 1.1920x over previous
//
#include <hip/hip_runtime.h>
#include <math.h>

namespace {
constexpr int kB = 256;
constexpr int kT = 64;
constexpr int kPhys = 3;
constexpr int kLat = 8;
constexpr int kNN = 128;
constexpr int kWin = 32;
constexpr int kPred = 64;
constexpr int kHPad = 132;     // padded row of hidden activations
constexpr int kDecRows = 96;   // 64 (x_ae) + 32 (new y_adv rows)
}

__device__ __forceinline__ double rdlane_f64(double x, int l) {
  const long long v = __double_as_longlong(x);
  const int lo = __builtin_amdgcn_readlane((int)(unsigned int)(v & 0xffffffffll), l);
  const int hi = __builtin_amdgcn_readlane((int)(v >> 32), l);
  const long long r = (((long long)hi) << 32) | (unsigned long long)(unsigned int)lo;
  return __longlong_as_double(r);
}

// 3 hidden layers 128->128 with relu, activations in hb (rows partitioned by
// 32-lane group: group g owns rows [g*RPG, (g+1)*RPG)), weights staged in LDS.
template<int NROWS>
__device__ __forceinline__ void hidden_layers(const float* __restrict__ wh,
                                              const float* __restrict__ bh_all,
                                              float (*__restrict__ hb)[kHPad],
                                              float* __restrict__ wst, int tid)
{
  const int g = tid >> 5;
  const int jb = (tid & 31) * 4;
  constexpr int RPG = NROWS / 16;
  for (int L = 0; L < 3; ++L) {
    __syncthreads();  // prev hb writes visible; prev wst reads complete
    const float4* __restrict__ Wv = (const float4*)(wh + (size_t)L * kNN * kNN);
    float4* wst4 = (float4*)wst;
#pragma unroll
    for (int i = 0; i < 8; ++i) wst4[tid + i * 512] = Wv[tid + i * 512];
    __syncthreads();
    float acc[RPG][4];
#pragma unroll
    for (int r = 0; r < RPG; ++r) { acc[r][0] = 0.f; acc[r][1] = 0.f; acc[r][2] = 0.f; acc[r][3] = 0.f; }
    for (int k4 = 0; k4 < kNN; k4 += 4) {
      const float4 w0 = *(const float4*)&wst[(k4 + 0) * kNN + jb];
      const float4 w1 = *(const float4*)&wst[(k4 + 1) * kNN + jb];
      const float4 w2 = *(const float4*)&wst[(k4 + 2) * kNN + jb];
      const float4 w3 = *(const float4*)&wst[(k4 + 3) * kNN + jb];
#pragma unroll
      for (int r = 0; r < RPG; ++r) {
        const float4 hv = *(const float4*)&hb[g * RPG + r][k4];
        acc[r][0] += hv.x * w0.x + hv.y * w1.x + hv.z * w2.x + hv.w * w3.x;
        acc[r][1] += hv.x * w0.y + hv.y * w1.y + hv.z * w2.y + hv.w * w3.y;
        acc[r][2] += hv.x * w0.z + hv.y * w1.z + hv.z * w2.z + hv.w * w3.z;
        acc[r][3] += hv.x * w0.w + hv.y * w1.w + hv.z * w2.w + hv.w * w3.w;
      }
    }
    const float* __restrict__ bh = bh_all + L * kNN;
    const float b0 = bh[jb + 0], b1 = bh[jb + 1], b2 = bh[jb + 2], b3 = bh[jb + 3];
    // rows are group-private: in-wave write after in-wave reads is safe
#pragma unroll
    for (int r = 0; r < RPG; ++r) {
      float4 o;
      o.x = fmaxf(acc[r][0] + b0, 0.f);
      o.y = fmaxf(acc[r][1] + b1, 0.f);
      o.z = fmaxf(acc[r][2] + b2, 0.f);
      o.w = fmaxf(acc[r][3] + b3, 0.f);
      *(float4*)&hb[g * RPG + r][jb] = o;
    }
  }
  __syncthreads();  // hb ready for cross-group readers
}

__global__ __launch_bounds__(512) void fused_kernel(
    const float* __restrict__ x,
    const float* __restrict__ ewin, const float* __restrict__ ebin,
    const float* __restrict__ ewh,  const float* __restrict__ ebh,
    const float* __restrict__ ewout,const float* __restrict__ ebout,
    const float* __restrict__ dwin, const float* __restrict__ dbin,
    const float* __restrict__ dwh,  const float* __restrict__ dbh,
    const float* __restrict__ dwout,const float* __restrict__ dbout,
    float* __restrict__ y_g, float* __restrict__ xae_g,
    float* __restrict__ xadv_g, float* __restrict__ yadv_g)
{
  __shared__ __align__(16) char us[kDecRows * kHPad * 4];  // 50688 B union
  __shared__ float wst[kNN * kNN];                         // 64 KB weight stage
  __shared__ float ybuf[kT][kLat + 1];
  __shared__ float yadv2[kWin][kLat + 1];
  __shared__ float inb[kT][4];

  float (*hb)[kHPad] = (float(*)[kHPad])us;
  const int tid = threadIdx.x;
  const int b = blockIdx.x;

  // ---- load x ----
  const float* __restrict__ xg = x + (size_t)b * kT * kPhys;
  for (int i = tid; i < kT * kPhys; i += 512) inb[i / 3][i % 3] = xg[i];
  __syncthreads();

  // ---- encoder input layer 3 -> 128 ----
  {
    const int j = tid & 127, rh = tid >> 7;
    const float w0 = ewin[j], w1 = ewin[kNN + j], w2 = ewin[2 * kNN + j];
    const float bj = ebin[j];
#pragma unroll
    for (int c = 0; c < 16; ++c) {
      const int r = 4 * c + rh;
      const float a = bj + inb[r][0] * w0 + inb[r][1] * w1 + inb[r][2] * w2;
      hb[r][j] = fmaxf(a, 0.f);
    }
  }
  hidden_layers<kT>(ewh, ebh, hb, wst, tid);

  // ---- encoder output layer 128 -> 8 ----
  {
    const int r = tid >> 3, o = tid & 7;
    float a = ebout[o];
    for (int k4 = 0; k4 < kNN; k4 += 4) {
      const float4 hv = *(const float4*)&hb[r][k4];
      a += hv.x * ewout[(k4 + 0) * kLat + o] + hv.y * ewout[(k4 + 1) * kLat + o]
         + hv.z * ewout[(k4 + 2) * kLat + o] + hv.w * ewout[(k4 + 3) * kLat + o];
    }
    ybuf[r][o] = a;
    y_g[(size_t)b * kT * kLat + tid] = a;  // tid == r*8+o
  }
  __syncthreads();  // ybuf ready; hb reads done -> DMD may overwrite union

  // ---- Hankel-DMD ----
  {
    double (*yd)[kT + 1]  = (double(*)[kT + 1])(us);          // 4160 B
    double (*P)[67]       = (double(*)[67])(us + 4160);       // 17152 B
    double (*Corr)[33]    = (double(*)[33])(us + 21312);      // 8448 B
    double (*KTm)[33]     = (double(*)[33])(us + 29760);      // 8184 B
    double (*Dv)[33]      = (double(*)[33])(us + 37944);      // 8448 B -> 46392

    yd[tid & 7][tid >> 3] = (double)ybuf[tid >> 3][tid & 7];  // 512 = 64*8
    __syncthreads();

    // P[d][t] = sum_l yd[l][t]*yd[l][t+d]
    for (int idx = tid; idx < 32 * 64; idx += 512) {
      const int d = idx >> 6, t = idx & 63;
      if (t + d < kT) {
        double s = 0.0;
#pragma unroll
        for (int l = 0; l < kLat; ++l) s += yd[l][t] * yd[l][t + d];
        P[d][t] = s;
      }
    }
    __syncthreads();

    // Corr[a][c] = sum_{r=0..32} P[|c-a|][min(a,c)+r]
    for (int idx = tid; idx < 32 * 32; idx += 512) {
      const int a = idx >> 5, c = idx & 31;
      const int d = (c >= a) ? (c - a) : (a - c);
      const int base = (c >= a) ? a : c;
      double s0 = 0.0, s1 = 0.0;
#pragma unroll
      for (int r = 0; r < 32; r += 2) { s0 += P[d][base + r]; s1 += P[d][base + r + 1]; }
      Corr[a][c] = s0 + s1 + P[d][base + 32];
    }
    __syncthreads();

    // single-wave register algebra: [G|C] -> [I|K], then d_{k+1} = K d_k
    if (tid < 64) {
      const int lane = tid;
      const int colidx = (lane <= 30) ? lane : (lane <= 61 ? lane - 30 : 1);
      double m[31];
#pragma unroll
      for (int i = 0; i < 31; ++i) m[i] = Corr[i][colidx];
#pragma unroll
      for (int k = 0; k < 31; ++k) {
        const double piv = rdlane_f64(m[k], k);
        const double pinv = 1.0 / piv;
        m[k] *= pinv;
#pragma unroll
        for (int i = 0; i < 31; ++i) {
          if (i == k) continue;
          const double bci = rdlane_f64(m[i], k);
          m[i] = fma(-bci, m[k], m[i]);
        }
      }
      if (lane >= 31 && lane < 62) {
        const int c = lane - 31;
#pragma unroll
        for (int i = 0; i < 31; ++i) KTm[i][c] = m[i];
      }
      const int ri = (lane < 31) ? lane : 0;
      double Kr[31];
#pragma unroll
      for (int j = 0; j < 31; ++j) Kr[j] = KTm[ri][j];

      double dv = Kr[30];  // d_0 = K[:,30]
      if (lane < 31) Dv[0][lane] = dv;
      for (int k = 0; k < 31; ++k) {
        double a0 = 0.0, a1 = 0.0, a2 = 0.0, a3 = 0.0;
#pragma unroll
        for (int j = 0; j < 31; ++j) {
          const double dj = rdlane_f64(dv, j);
          if ((j & 3) == 0) a0 = fma(Kr[j], dj, a0);
          else if ((j & 3) == 1) a1 = fma(Kr[j], dj, a1);
          else if ((j & 3) == 2) a2 = fma(Kr[j], dj, a2);
          else a3 = fma(Kr[j], dj, a3);
        }
        dv = (a0 + a1) + (a2 + a3);
        if (lane < 31) Dv[k + 1][lane] = dv;
      }
    }
    __syncthreads();

    float* __restrict__ ob = yadv_g + (size_t)b * kPred * kLat;
    if (tid < 256) {
      // p < 32: exact copy of y
      ob[tid] = ybuf[tid >> 3][tid & 7];
    } else {
      // p = 32+k: sum_j y[l][j+1] * d_k[j]
      const int q = tid - 256;
      const int k = q >> 3, l = q & 7;
      double a0 = 0.0, a1 = 0.0, a2 = 0.0, a3 = 0.0;
#pragma unroll
      for (int j = 0; j < 31; ++j) {
        if ((j & 3) == 0) a0 = fma(yd[l][j + 1], Dv[k][j], a0);
        else if ((j & 3) == 1) a1 = fma(yd[l][j + 1], Dv[k][j], a1);
        else if ((j & 3) == 2) a2 = fma(yd[l][j + 1], Dv[k][j], a2);
        else a3 = fma(yd[l][j + 1], Dv[k][j], a3);
      }
      const float v = (float)((a0 + a1) + (a2 + a3));
      ob[256 + q] = v;
      yadv2[k][l] = v;
    }
    __syncthreads();  // yd/Dv reads done -> decoder may overwrite union
  }

  // ---- decoder input layer 8 -> 128, 96 rows (64 from y, 32 new y_adv) ----
  {
    const int j = tid & 127, rh = tid >> 7;
    float wr[kLat];
#pragma unroll
    for (int k = 0; k < kLat; ++k) wr[k] = dwin[k * kNN + j];
    const float bj = dbin[j];
#pragma unroll
    for (int c = 0; c < 24; ++c) {
      const int r = 4 * c + rh;
      const float* __restrict__ src = (r < kT) ? &ybuf[r][0] : &yadv2[r - kT][0];
      float a = bj;
#pragma unroll
      for (int k = 0; k < kLat; ++k) a += src[k] * wr[k];
      hb[r][j] = fmaxf(a, 0.f);
    }
  }
  hidden_layers<kDecRows>(dwh, dbh, hb, wst, tid);

  // ---- decoder output layer 128 -> 3; x_adv[:32] = x_ae[:32] (y_adv[:32]==y[:32]) ----
  for (int idx = tid; idx < kDecRows * kPhys; idx += 512) {
    const int r = idx / 3, o = idx - r * 3;
    float a = dbout[o];
    for (int k4 = 0; k4 < kNN; k4 += 4) {
      const float4 hv = *(const float4*)&hb[r][k4];
      a += hv.x * dwout[(k4 + 0) * kPhys + o] + hv.y * dwout[(k4 + 1) * kPhys + o]
         + hv.z * dwout[(k4 + 2) * kPhys + o] + hv.w * dwout[(k4 + 3) * kPhys + o];
    }
    if (r < kT) {
      xae_g[(size_t)b * kT * kPhys + idx] = a;
      if (r < kWin) xadv_g[(size_t)b * kT * kPhys + idx] = a;
    } else {
      const int rr = r - kT + kWin;  // 32..63
      xadv_g[(size_t)b * kT * kPhys + rr * kPhys + o] = a;
    }
  }
}

extern "C" void kernel_launch(void* const* d_in, const int* in_sizes, int n_in,
                              void* d_out, int out_size, void* d_ws, size_t ws_size,
                              hipStream_t stream)
{
  const float* x         = (const float*)d_in[0];
  const float* enc_w_in  = (const float*)d_in[1];
  const float* enc_b_in  = (const float*)d_in[2];
  const float* enc_w_h   = (const float*)d_in[3];
  const float* enc_b_h   = (const float*)d_in[4];
  const float* enc_w_out = (const float*)d_in[5];
  const float* enc_b_out = (const float*)d_in[6];
  const float* dec_w_in  = (const float*)d_in[7];
  const float* dec_b_in  = (const float*)d_in[8];
  const float* dec_w_h   = (const float*)d_in[9];
  const float* dec_b_h   = (const float*)d_in[10];
  const float* dec_w_out = (const float*)d_in[11];
  const float* dec_b_out = (const float*)d_in[12];

  float* out   = (float*)d_out;
  float* y     = out;                                  // (B,T,8)   131072
  float* x_ae  = out + (size_t)kB * kT * kLat;         // (B,T,3)    49152
  float* x_adv = x_ae + (size_t)kB * kT * kPhys;       // (B,T,3)    49152
  float* y_adv = x_adv + (size_t)kB * kT * kPhys;      // (B,64,8)  131072

  fused_kernel<<<kB, 512, 0, stream>>>(
      x, enc_w_in, enc_b_in, enc_w_h, enc_b_h, enc_w_out, enc_b_out,
      dec_w_in, dec_b_in, dec_w_h, dec_b_h, dec_w_out, dec_b_out,
      y, x_ae, x_adv, y_adv);
}

// Round 4
// 61.616 us; speedup vs baseline: 4.6784x; 1.6150x over previous
//
#include <hip/hip_runtime.h>
#include <math.h>

namespace {
constexpr int kB = 256;
constexpr int kT = 64;
constexpr int kPhys = 3;
constexpr int kLat = 8;
constexpr int kNN = 128;
constexpr int kWin = 32;
constexpr int kPred = 64;
constexpr int kHPad = 132;     // padded row of f32 activations (last hidden layer)
constexpr int kDecRows = 96;   // 64 (x_ae) + 32 (new y_adv rows)
constexpr int kFragElems = 6 * 4 * 64 * 8;  // max M-tiles(6) x q(4) x lane x e
}

typedef short bf16x8 __attribute__((ext_vector_type(8)));
typedef float f32x4 __attribute__((ext_vector_type(4)));

__device__ __forceinline__ double rdlane_f64(double x, int l) {
  const long long v = __double_as_longlong(x);
  const int lo = __builtin_amdgcn_readlane((int)(unsigned int)(v & 0xffffffffll), l);
  const int hi = __builtin_amdgcn_readlane((int)(v >> 32), l);
  const long long r = (((long long)hi) << 32) | (unsigned long long)(unsigned int)lo;
  return __longlong_as_double(r);
}

__device__ __forceinline__ unsigned rneb(float f) {  // f32 -> bf16 bits (RNE)
  const unsigned u = __float_as_uint(f);
  return (u + 0x7fffu + ((u >> 16) & 1u)) >> 16;
}
// exact 3-way split: a = b1 + b2 + b3 (each bf16) + O(2^-25)|a|
__device__ __forceinline__ void split3(float a, short& s1, short& s2, short& s3) {
  const unsigned b1 = rneb(a);
  const float f1 = __uint_as_float(b1 << 16);
  const float r1 = a - f1;
  const unsigned b2 = rneb(r1);
  const float f2 = __uint_as_float(b2 << 16);
  const float r2 = r1 - f2;
  const unsigned b3 = rneb(r2);
  s1 = (short)b1; s2 = (short)b2; s3 = (short)b3;
}

// One hidden layer (128->128, relu) via MFMA f32-emulation (6 bf16 products).
// Wave w owns N-tile w (cols 16w..16w+15); iterates M-tiles in pairs.
// A-frags read from LDS (packed fragment order); B-frags built from global W.
template<int MT, bool TO_FRAG>
__device__ __forceinline__ void mfma_layer(
    const float* __restrict__ W, const float* __restrict__ bias,
    const short* __restrict__ A1, const short* __restrict__ A2,
    const short* __restrict__ A3,
    short* __restrict__ D1, short* __restrict__ D2, short* __restrict__ D3,
    float* __restrict__ hbout, int tid)
{
  const int wid = tid >> 6, l = tid & 63;
  const int colg = 16 * wid + (l & 15);
  const int krow = 8 * (l >> 4);
  bf16x8 B1[4], B2[4], B3[4];
#pragma unroll
  for (int q = 0; q < 4; ++q) {
#pragma unroll
    for (int e = 0; e < 8; ++e) {
      const float w = W[(32 * q + krow + e) * kNN + colg];
      short s1, s2, s3; split3(w, s1, s2, s3);
      B1[q][e] = s1; B2[q][e] = s2; B3[q][e] = s3;
    }
  }
  const float bj = bias[colg];
  const int qt = colg >> 5, sub = (colg >> 3) & 3, et = colg & 7;
  const int rbase = (l >> 4) * 4;
#pragma unroll
  for (int mp = 0; mp < MT; mp += 2) {
    f32x4 acc0 = {bj, bj, bj, bj}, acc1 = {bj, bj, bj, bj};
#pragma unroll
    for (int q = 0; q < 4; ++q) {
      const int o0 = ((mp * 4 + q) * 64 + l) * 8;
      const int o1 = (((mp + 1) * 4 + q) * 64 + l) * 8;
      const bf16x8 a01 = *(const bf16x8*)&A1[o0];
      const bf16x8 a02 = *(const bf16x8*)&A2[o0];
      const bf16x8 a03 = *(const bf16x8*)&A3[o0];
      const bf16x8 a11 = *(const bf16x8*)&A1[o1];
      const bf16x8 a12 = *(const bf16x8*)&A2[o1];
      const bf16x8 a13 = *(const bf16x8*)&A3[o1];
      acc0 = __builtin_amdgcn_mfma_f32_16x16x32_bf16(a01, B1[q], acc0, 0, 0, 0);
      acc1 = __builtin_amdgcn_mfma_f32_16x16x32_bf16(a11, B1[q], acc1, 0, 0, 0);
      acc0 = __builtin_amdgcn_mfma_f32_16x16x32_bf16(a01, B2[q], acc0, 0, 0, 0);
      acc1 = __builtin_amdgcn_mfma_f32_16x16x32_bf16(a11, B2[q], acc1, 0, 0, 0);
      acc0 = __builtin_amdgcn_mfma_f32_16x16x32_bf16(a02, B1[q], acc0, 0, 0, 0);
      acc1 = __builtin_amdgcn_mfma_f32_16x16x32_bf16(a12, B1[q], acc1, 0, 0, 0);
      acc0 = __builtin_amdgcn_mfma_f32_16x16x32_bf16(a01, B3[q], acc0, 0, 0, 0);
      acc1 = __builtin_amdgcn_mfma_f32_16x16x32_bf16(a11, B3[q], acc1, 0, 0, 0);
      acc0 = __builtin_amdgcn_mfma_f32_16x16x32_bf16(a02, B2[q], acc0, 0, 0, 0);
      acc1 = __builtin_amdgcn_mfma_f32_16x16x32_bf16(a12, B2[q], acc1, 0, 0, 0);
      acc0 = __builtin_amdgcn_mfma_f32_16x16x32_bf16(a03, B1[q], acc0, 0, 0, 0);
      acc1 = __builtin_amdgcn_mfma_f32_16x16x32_bf16(a13, B1[q], acc1, 0, 0, 0);
    }
#pragma unroll
    for (int half = 0; half < 2; ++half) {
      const int m = mp + half;
#pragma unroll
      for (int r = 0; r < 4; ++r) {
        const float v = fmaxf(half ? acc1[r] : acc0[r], 0.f);
        if constexpr (TO_FRAG) {
          short s1, s2, s3; split3(v, s1, s2, s3);
          const int off = ((m * 4 + qt) * 64 + (rbase + r + 16 * sub)) * 8 + et;
          D1[off] = s1; D2[off] = s2; D3[off] = s3;
        } else {
          hbout[(m * 16 + rbase + r) * kHPad + colg] = v;
        }
      }
    }
  }
}

__global__ __launch_bounds__(512) void fused_kernel(
    const float* __restrict__ x,
    const float* __restrict__ ewin, const float* __restrict__ ebin,
    const float* __restrict__ ewh,  const float* __restrict__ ebh,
    const float* __restrict__ ewout,const float* __restrict__ ebout,
    const float* __restrict__ dwin, const float* __restrict__ dbin,
    const float* __restrict__ dwh,  const float* __restrict__ dbh,
    const float* __restrict__ dwout,const float* __restrict__ dbout,
    float* __restrict__ y_g, float* __restrict__ xae_g,
    float* __restrict__ xadv_g, float* __restrict__ yadv_g)
{
  __shared__ __align__(16) char regA[kFragElems * 3 * 2];  // 73728 B: frag buf A / DMD scratch
  __shared__ __align__(16) char regB[kFragElems * 3 * 2];  // 73728 B: frag buf B / hb f32
  __shared__ float ybuf[kT][kLat + 1];
  __shared__ float yadv2[kWin][kLat + 1];
  __shared__ float inb[kT][4];

  short* sA1 = (short*)regA;
  short* sA2 = sA1 + kFragElems;
  short* sA3 = sA2 + kFragElems;
  short* sB1 = (short*)regB;
  short* sB2 = sB1 + kFragElems;
  short* sB3 = sB2 + kFragElems;
  float* hb  = (float*)regB;   // [96][132] f32, aliases frag buf B

  const int tid = threadIdx.x;
  const int b = blockIdx.x;

  // ---- load x ----
  const float* __restrict__ xg = x + (size_t)b * kT * kPhys;
  for (int i = tid; i < kT * kPhys; i += 512) inb[i / 3][i % 3] = xg[i];
  __syncthreads();

  // ---- encoder input layer 3 -> 128, scatter to frag buf A ----
  {
    const int j = tid & 127, rh = tid >> 7;
    const float w0 = ewin[j], w1 = ewin[kNN + j], w2 = ewin[2 * kNN + j];
    const float bj = ebin[j];
    const int qt = j >> 5, sub = (j >> 3) & 3, et = j & 7;
#pragma unroll
    for (int c = 0; c < 16; ++c) {
      const int r = 4 * c + rh;
      const float a = fmaxf(bj + inb[r][0] * w0 + inb[r][1] * w1 + inb[r][2] * w2, 0.f);
      short s1, s2, s3; split3(a, s1, s2, s3);
      const int off = (((r >> 4) * 4 + qt) * 64 + ((r & 15) + 16 * sub)) * 8 + et;
      sA1[off] = s1; sA2[off] = s2; sA3[off] = s3;
    }
  }
  __syncthreads();
  mfma_layer<4, true >(ewh,                 ebh,           sA1, sA2, sA3, sB1, sB2, sB3, hb, tid);
  __syncthreads();
  mfma_layer<4, true >(ewh + 1 * kNN * kNN, ebh + 1 * kNN, sB1, sB2, sB3, sA1, sA2, sA3, hb, tid);
  __syncthreads();
  mfma_layer<4, false>(ewh + 2 * kNN * kNN, ebh + 2 * kNN, sA1, sA2, sA3, sB1, sB2, sB3, hb, tid);
  __syncthreads();

  // ---- encoder output layer 128 -> 8 ----
  {
    const int r = tid >> 3, o = tid & 7;
    float a = ebout[o];
    for (int k4 = 0; k4 < kNN; k4 += 4) {
      const float4 hv = *(const float4*)&hb[r * kHPad + k4];
      a += hv.x * ewout[(k4 + 0) * kLat + o] + hv.y * ewout[(k4 + 1) * kLat + o]
         + hv.z * ewout[(k4 + 2) * kLat + o] + hv.w * ewout[(k4 + 3) * kLat + o];
    }
    ybuf[r][o] = a;
    y_g[(size_t)b * kT * kLat + tid] = a;
  }
  __syncthreads();  // ybuf ready; regA free for DMD

  // ---- Hankel-DMD (f64, unchanged math) ----
  {
    double (*yd)[kT + 1]  = (double(*)[kT + 1])(regA);
    double (*P)[67]       = (double(*)[67])(regA + 4160);
    double (*Corr)[33]    = (double(*)[33])(regA + 21312);
    double (*KTm)[33]     = (double(*)[33])(regA + 29760);
    double (*Dv)[33]      = (double(*)[33])(regA + 37944);

    yd[tid & 7][tid >> 3] = (double)ybuf[tid >> 3][tid & 7];  // 512 = 64*8
    __syncthreads();

    for (int idx = tid; idx < 32 * 64; idx += 512) {
      const int d = idx >> 6, t = idx & 63;
      if (t + d < kT) {
        double s = 0.0;
#pragma unroll
        for (int l = 0; l < kLat; ++l) s += yd[l][t] * yd[l][t + d];
        P[d][t] = s;
      }
    }
    __syncthreads();

    for (int idx = tid; idx < 32 * 32; idx += 512) {
      const int a = idx >> 5, c = idx & 31;
      const int d = (c >= a) ? (c - a) : (a - c);
      const int base = (c >= a) ? a : c;
      double s0 = 0.0, s1 = 0.0;
#pragma unroll
      for (int r = 0; r < 32; r += 2) { s0 += P[d][base + r]; s1 += P[d][base + r + 1]; }
      Corr[a][c] = s0 + s1 + P[d][base + 32];
    }
    __syncthreads();

    if (tid < 64) {
      const int lane = tid;
      const int colidx = (lane <= 30) ? lane : (lane <= 61 ? lane - 30 : 1);
      double m[31];
#pragma unroll
      for (int i = 0; i < 31; ++i) m[i] = Corr[i][colidx];
#pragma unroll
      for (int k = 0; k < 31; ++k) {
        const double piv = rdlane_f64(m[k], k);
        const double pinv = 1.0 / piv;
        m[k] *= pinv;
#pragma unroll
        for (int i = 0; i < 31; ++i) {
          if (i == k) continue;
          const double bci = rdlane_f64(m[i], k);
          m[i] = fma(-bci, m[k], m[i]);
        }
      }
      if (lane >= 31 && lane < 62) {
        const int c = lane - 31;
#pragma unroll
        for (int i = 0; i < 31; ++i) KTm[i][c] = m[i];
      }
      const int ri = (lane < 31) ? lane : 0;
      double Kr[31];
#pragma unroll
      for (int j = 0; j < 31; ++j) Kr[j] = KTm[ri][j];

      double dv = Kr[30];  // d_0 = K[:,30]
      if (lane < 31) Dv[0][lane] = dv;
      for (int k = 0; k < 31; ++k) {
        double a0 = 0.0, a1 = 0.0, a2 = 0.0, a3 = 0.0;
#pragma unroll
        for (int j = 0; j < 31; ++j) {
          const double dj = rdlane_f64(dv, j);
          if ((j & 3) == 0) a0 = fma(Kr[j], dj, a0);
          else if ((j & 3) == 1) a1 = fma(Kr[j], dj, a1);
          else if ((j & 3) == 2) a2 = fma(Kr[j], dj, a2);
          else a3 = fma(Kr[j], dj, a3);
        }
        dv = (a0 + a1) + (a2 + a3);
        if (lane < 31) Dv[k + 1][lane] = dv;
      }
    }
    __syncthreads();

    float* __restrict__ ob = yadv_g + (size_t)b * kPred * kLat;
    if (tid < 256) {
      ob[tid] = ybuf[tid >> 3][tid & 7];  // p < 32: exact copy of y
    } else {
      const int q = tid - 256;
      const int k = q >> 3, l = q & 7;
      double a0 = 0.0, a1 = 0.0, a2 = 0.0, a3 = 0.0;
#pragma unroll
      for (int j = 0; j < 31; ++j) {
        if ((j & 3) == 0) a0 = fma(yd[l][j + 1], Dv[k][j], a0);
        else if ((j & 3) == 1) a1 = fma(yd[l][j + 1], Dv[k][j], a1);
        else if ((j & 3) == 2) a2 = fma(yd[l][j + 1], Dv[k][j], a2);
        else a3 = fma(yd[l][j + 1], Dv[k][j], a3);
      }
      const float v = (float)((a0 + a1) + (a2 + a3));
      ob[256 + q] = v;
      yadv2[k][l] = v;
    }
    __syncthreads();  // yd/Dv reads done; regA free for decoder frags
  }

  // ---- decoder input layer 8 -> 128, 96 rows, scatter to frag buf A ----
  {
    const int j = tid & 127, rh = tid >> 7;
    float wr[kLat];
#pragma unroll
    for (int k = 0; k < kLat; ++k) wr[k] = dwin[k * kNN + j];
    const float bj = dbin[j];
    const int qt = j >> 5, sub = (j >> 3) & 3, et = j & 7;
#pragma unroll
    for (int c = 0; c < 24; ++c) {
      const int r = 4 * c + rh;
      const float* __restrict__ src = (r < kT) ? &ybuf[r][0] : &yadv2[r - kT][0];
      float a = bj;
#pragma unroll
      for (int k = 0; k < kLat; ++k) a += src[k] * wr[k];
      a = fmaxf(a, 0.f);
      short s1, s2, s3; split3(a, s1, s2, s3);
      const int off = (((r >> 4) * 4 + qt) * 64 + ((r & 15) + 16 * sub)) * 8 + et;
      sA1[off] = s1; sA2[off] = s2; sA3[off] = s3;
    }
  }
  __syncthreads();
  mfma_layer<6, true >(dwh,                 dbh,           sA1, sA2, sA3, sB1, sB2, sB3, hb, tid);
  __syncthreads();
  mfma_layer<6, true >(dwh + 1 * kNN * kNN, dbh + 1 * kNN, sB1, sB2, sB3, sA1, sA2, sA3, hb, tid);
  __syncthreads();
  mfma_layer<6, false>(dwh + 2 * kNN * kNN, dbh + 2 * kNN, sA1, sA2, sA3, sB1, sB2, sB3, hb, tid);
  __syncthreads();

  // ---- decoder output layer 128 -> 3 ----
  for (int idx = tid; idx < kDecRows * kPhys; idx += 512) {
    const int r = idx / 3, o = idx - r * 3;
    float a = dbout[o];
    for (int k4 = 0; k4 < kNN; k4 += 4) {
      const float4 hv = *(const float4*)&hb[r * kHPad + k4];
      a += hv.x * dwout[(k4 + 0) * kPhys + o] + hv.y * dwout[(k4 + 1) * kPhys + o]
         + hv.z * dwout[(k4 + 2) * kPhys + o] + hv.w * dwout[(k4 + 3) * kPhys + o];
    }
    if (r < kT) {
      xae_g[(size_t)b * kT * kPhys + idx] = a;
      if (r < kWin) xadv_g[(size_t)b * kT * kPhys + idx] = a;
    } else {
      const int rr = r - kT + kWin;  // 32..63
      xadv_g[(size_t)b * kT * kPhys + rr * kPhys + o] = a;
    }
  }
}

extern "C" void kernel_launch(void* const* d_in, const int* in_sizes, int n_in,
                              void* d_out, int out_size, void* d_ws, size_t ws_size,
                              hipStream_t stream)
{
  const float* x         = (const float*)d_in[0];
  const float* enc_w_in  = (const float*)d_in[1];
  const float* enc_b_in  = (const float*)d_in[2];
  const float* enc_w_h   = (const float*)d_in[3];
  const float* enc_b_h   = (const float*)d_in[4];
  const float* enc_w_out = (const float*)d_in[5];
  const float* enc_b_out = (const float*)d_in[6];
  const float* dec_w_in  = (const float*)d_in[7];
  const float* dec_b_in  = (const float*)d_in[8];
  const float* dec_w_h   = (const float*)d_in[9];
  const float* dec_b_h   = (const float*)d_in[10];
  const float* dec_w_out = (const float*)d_in[11];
  const float* dec_b_out = (const float*)d_in[12];

  float* out   = (float*)d_out;
  float* y     = out;                                  // (B,T,8)   131072
  float* x_ae  = out + (size_t)kB * kT * kLat;         // (B,T,3)    49152
  float* x_adv = x_ae + (size_t)kB * kT * kPhys;       // (B,T,3)    49152
  float* y_adv = x_adv + (size_t)kB * kT * kPhys;      // (B,64,8)  131072

  fused_kernel<<<kB, 512, 0, stream>>>(
      x, enc_w_in, enc_b_in, enc_w_h, enc_b_h, enc_w_out, enc_b_out,
      dec_w_in, dec_b_in, dec_w_h, dec_b_h, dec_w_out, dec_b_out,
      y, x_ae, x_adv, y_adv);
}

// Round 5
// 60.426 us; speedup vs baseline: 4.7706x; 1.0197x over previous
//
#include <hip/hip_runtime.h>
#include <math.h>

namespace {
constexpr int kB = 256;
constexpr int kT = 64;
constexpr int kPhys = 3;
constexpr int kLat = 8;
constexpr int kNN = 128;
constexpr int kWin = 32;
constexpr int kPred = 64;
constexpr int kHRow = 132;       // padded f32 activation row (132 % 8 == 4 -> 2-way banks)
constexpr int kDecRows = 96;     // 64 (x_ae) + 32 (new y_adv rows)
constexpr int kThreads = 1024;
}

typedef short bf16x8 __attribute__((ext_vector_type(8)));
typedef float f32x4 __attribute__((ext_vector_type(4)));

__device__ __forceinline__ double rdlane_f64(double x, int l) {
  const long long v = __double_as_longlong(x);
  const int lo = __builtin_amdgcn_readlane((int)(unsigned int)(v & 0xffffffffll), l);
  const int hi = __builtin_amdgcn_readlane((int)(v >> 32), l);
  const long long r = (((long long)hi) << 32) | (unsigned long long)(unsigned int)lo;
  return __longlong_as_double(r);
}

__device__ __forceinline__ unsigned rneb(float f) {  // f32 -> bf16 bits (RNE)
  const unsigned u = __float_as_uint(f);
  return (u + 0x7fffu + ((u >> 16) & 1u)) >> 16;
}
// 3-way split: a ~= b1+b2+b3 with O(2^-25)|a| error (f32-equivalent products)
__device__ __forceinline__ void split3(float a, short& s1, short& s2, short& s3) {
  const unsigned b1 = rneb(a);
  const float f1 = __uint_as_float(b1 << 16);
  const float r1 = a - f1;
  const unsigned b2 = rneb(r1);
  const float f2 = __uint_as_float(b2 << 16);
  s1 = (short)b1; s2 = (short)b2; s3 = (short)rneb(r1 - f2);
}
// 2-way split: a ~= b1+b2 with O(2^-17)|a| error (decoder-only; terminal outputs)
__device__ __forceinline__ void split2(float a, short& s1, short& s2) {
  const unsigned b1 = rneb(a);
  const float f1 = __uint_as_float(b1 << 16);
  s1 = (short)b1; s2 = (short)rneb(a - f1);
}

// ---- pack: hb (natural f32 [rows][132]) -> A-fragment planes (contiguous) ----
template<int MT, int SPLITS>
__device__ __forceinline__ void pack_frag(const float* __restrict__ hb,
                                          short* __restrict__ frag, int tid)
{
  constexpr int PLANE = MT * 4 * 64 * 8;
  for (int idx = tid; idx < MT * 256; idx += kThreads) {
    const int m = idx >> 8, q = (idx >> 6) & 3, l = idx & 63;
    const int row = 16 * m + (l & 15), col = 32 * q + 8 * (l >> 4);
    const float4 f0 = *(const float4*)&hb[row * kHRow + col];
    const float4 f1 = *(const float4*)&hb[row * kHRow + col + 4];
    const float f[8] = {f0.x, f0.y, f0.z, f0.w, f1.x, f1.y, f1.z, f1.w};
    bf16x8 p1, p2, p3;
#pragma unroll
    for (int e = 0; e < 8; ++e) {
      if constexpr (SPLITS == 3) {
        short s1, s2, s3; split3(f[e], s1, s2, s3);
        p1[e] = s1; p2[e] = s2; p3[e] = s3;
      } else {
        short s1, s2; split2(f[e], s1, s2);
        p1[e] = s1; p2[e] = s2;
      }
    }
    const int o = ((m * 4 + q) * 64 + l) * 8;
    *(bf16x8*)&frag[o] = p1;
    *(bf16x8*)&frag[PLANE + o] = p2;
    if constexpr (SPLITS == 3) *(bf16x8*)&frag[2 * PLANE + o] = p3;
  }
}

// ---- one hidden layer 128->128 (+relu) via MFMA; wave (n-tile, m-set) ----
template<int MPW, int SPLITS>
__device__ __forceinline__ void mfma_layer(
    const float* __restrict__ W, const float* __restrict__ bias,
    const short* __restrict__ frag, float* __restrict__ hb, int tid)
{
  constexpr int MT = 2 * MPW;
  constexpr int PLANE = MT * 4 * 64 * 8;
  const int w = tid >> 6, l = tid & 63;
  const int n = w & 7, m0 = (w >> 3) * MPW;
  const int colg = 16 * n + (l & 15);
  const int krow = 8 * (l >> 4);
  bf16x8 B1[4], B2[4], B3[4];
#pragma unroll
  for (int q = 0; q < 4; ++q) {
#pragma unroll
    for (int e = 0; e < 8; ++e) {
      const float wv = W[(32 * q + krow + e) * kNN + colg];
      if constexpr (SPLITS == 3) {
        short s1, s2, s3; split3(wv, s1, s2, s3);
        B1[q][e] = s1; B2[q][e] = s2; B3[q][e] = s3;
      } else {
        short s1, s2; split2(wv, s1, s2);
        B1[q][e] = s1; B2[q][e] = s2;
      }
    }
  }
  const float bj = bias[colg];
  f32x4 acc[MPW];
#pragma unroll
  for (int mi = 0; mi < MPW; ++mi) acc[mi] = {bj, bj, bj, bj};
#pragma unroll
  for (int q = 0; q < 4; ++q) {
#pragma unroll
    for (int mi = 0; mi < MPW; ++mi) {
      const int o = (((m0 + mi) * 4 + q) * 64 + l) * 8;
      const bf16x8 a1 = *(const bf16x8*)&frag[o];
      const bf16x8 a2 = *(const bf16x8*)&frag[PLANE + o];
      acc[mi] = __builtin_amdgcn_mfma_f32_16x16x32_bf16(a1, B1[q], acc[mi], 0, 0, 0);
      acc[mi] = __builtin_amdgcn_mfma_f32_16x16x32_bf16(a1, B2[q], acc[mi], 0, 0, 0);
      acc[mi] = __builtin_amdgcn_mfma_f32_16x16x32_bf16(a2, B1[q], acc[mi], 0, 0, 0);
      if constexpr (SPLITS == 3) {
        const bf16x8 a3 = *(const bf16x8*)&frag[2 * PLANE + o];
        acc[mi] = __builtin_amdgcn_mfma_f32_16x16x32_bf16(a1, B3[q], acc[mi], 0, 0, 0);
        acc[mi] = __builtin_amdgcn_mfma_f32_16x16x32_bf16(a2, B2[q], acc[mi], 0, 0, 0);
        acc[mi] = __builtin_amdgcn_mfma_f32_16x16x32_bf16(a3, B1[q], acc[mi], 0, 0, 0);
      }
    }
  }
  const int rbase = (l >> 4) * 4;
#pragma unroll
  for (int mi = 0; mi < MPW; ++mi)
#pragma unroll
    for (int r = 0; r < 4; ++r)
      hb[(16 * (m0 + mi) + rbase + r) * kHRow + colg] = fmaxf(acc[mi][r], 0.f);
}

__global__ __launch_bounds__(kThreads, 4) void fused_kernel(
    const float* __restrict__ x,
    const float* __restrict__ ewin, const float* __restrict__ ebin,
    const float* __restrict__ ewh,  const float* __restrict__ ebh,
    const float* __restrict__ ewout,const float* __restrict__ ebout,
    const float* __restrict__ dwin, const float* __restrict__ dbin,
    const float* __restrict__ dwh,  const float* __restrict__ dbh,
    const float* __restrict__ dwout,const float* __restrict__ dbout,
    float* __restrict__ y_g, float* __restrict__ xae_g,
    float* __restrict__ xadv_g, float* __restrict__ yadv_g)
{
  __shared__ float hb[kDecRows * kHRow];            // 50688 B, natural activations
  __shared__ __align__(16) char fragbuf[49152];     // frag planes / DMD f64 scratch
  __shared__ float ybuf[kT][kLat + 1];
  __shared__ float yadv2[kWin][kLat + 1];
  __shared__ float inb[kT][4];

  short* frag = (short*)fragbuf;
  const int tid = threadIdx.x;
  const int b = blockIdx.x;

  // ---- load x ----
  const float* __restrict__ xg = x + (size_t)b * kT * kPhys;
  for (int i = tid; i < kT * kPhys; i += kThreads) inb[i / 3][i % 3] = xg[i];
  __syncthreads();

  // ---- encoder input layer 3 -> 128 (natural write) ----
  {
    const int j = tid & 127, rg = tid >> 7;  // rg 0..7, 8 rows each
    const float w0 = ewin[j], w1 = ewin[kNN + j], w2 = ewin[2 * kNN + j];
    const float bj = ebin[j];
#pragma unroll
    for (int rr = 0; rr < 8; ++rr) {
      const int r = rg * 8 + rr;
      hb[r * kHRow + j] = fmaxf(bj + inb[r][0] * w0 + inb[r][1] * w1 + inb[r][2] * w2, 0.f);
    }
  }
  __syncthreads();

  // ---- encoder hidden layers (3-split, f32-exact) ----
#pragma unroll
  for (int L = 0; L < 3; ++L) {
    pack_frag<4, 3>(hb, frag, tid);
    __syncthreads();
    mfma_layer<2, 3>(ewh + (size_t)L * kNN * kNN, ebh + L * kNN, frag, hb, tid);
    __syncthreads();
  }

  // ---- encoder output layer 128 -> 8 ----
  if (tid < 512) {
    const int r = tid >> 3, o = tid & 7;
    float a = ebout[o];
    for (int k4 = 0; k4 < kNN; k4 += 4) {
      const float4 hv = *(const float4*)&hb[r * kHRow + k4];
      a += hv.x * ewout[(k4 + 0) * kLat + o] + hv.y * ewout[(k4 + 1) * kLat + o]
         + hv.z * ewout[(k4 + 2) * kLat + o] + hv.w * ewout[(k4 + 3) * kLat + o];
    }
    ybuf[r][o] = a;
    y_g[(size_t)b * kT * kLat + tid] = a;
  }
  __syncthreads();  // ybuf ready; frag region free for DMD

  // ---- Hankel-DMD (f64, exact-math rewrite) ----
  {
    double* dmd = (double*)fragbuf;
    double* yd   = dmd;           // [8][65]
    double* P    = dmd + 520;     // [32][67]
    double* Corr = dmd + 2664;    // [32][33]
    double* KTm  = dmd + 3720;    // [31][33]
    double* Dv   = dmd + 4743;    // [32][33]  (ends 5799 dbl = 46392 B)

    if (tid < 512) yd[(tid & 7) * 65 + (tid >> 3)] = (double)ybuf[tid >> 3][tid & 7];
    __syncthreads();

    for (int idx = tid; idx < 32 * 64; idx += kThreads) {
      const int d = idx >> 6, t = idx & 63;
      if (t + d < kT) {
        double s = 0.0;
#pragma unroll
        for (int l = 0; l < kLat; ++l) s += yd[l * 65 + t] * yd[l * 65 + t + d];
        P[d * 67 + t] = s;
      }
    }
    __syncthreads();

    if (tid < 1024) {
      const int a = tid >> 5, c = tid & 31;
      const int d = (c >= a) ? (c - a) : (a - c);
      const int base = (c >= a) ? a : c;
      double s0 = 0.0, s1 = 0.0;
#pragma unroll
      for (int r = 0; r < 32; r += 2) { s0 += P[d * 67 + base + r]; s1 += P[d * 67 + base + r + 1]; }
      Corr[a * 33 + c] = s0 + s1 + P[d * 67 + base + 32];
    }
    __syncthreads();

    // single-wave register Gauss-Jordan [G|C] -> [I|K], then power iteration
    if (tid < 64) {
      const int lane = tid;
      const int colidx = (lane <= 30) ? lane : (lane <= 61 ? lane - 30 : 1);
      double m[31];
#pragma unroll
      for (int i = 0; i < 31; ++i) m[i] = Corr[i * 33 + colidx];
#pragma unroll
      for (int k = 0; k < 31; ++k) {
        const double piv = rdlane_f64(m[k], k);
        const double pinv = 1.0 / piv;
        m[k] *= pinv;
#pragma unroll
        for (int i = 0; i < 31; ++i) {
          if (i == k) continue;
          const double bci = rdlane_f64(m[i], k);
          m[i] = fma(-bci, m[k], m[i]);
        }
      }
      if (lane >= 31 && lane < 62) {
        const int c = lane - 31;
#pragma unroll
        for (int i = 0; i < 31; ++i) KTm[i * 33 + c] = m[i];
      }
      const int ri = (lane < 31) ? lane : 0;
      double Kr[31];
#pragma unroll
      for (int j = 0; j < 31; ++j) Kr[j] = KTm[ri * 33 + j];

      double dv = Kr[30];  // d_0 = K[:,30]
      if (lane < 31) Dv[0 * 33 + lane] = dv;
      for (int k = 0; k < 31; ++k) {
        double a0 = 0.0, a1 = 0.0, a2 = 0.0, a3 = 0.0;
#pragma unroll
        for (int j = 0; j < 31; ++j) {
          const double dj = rdlane_f64(dv, j);
          if ((j & 3) == 0) a0 = fma(Kr[j], dj, a0);
          else if ((j & 3) == 1) a1 = fma(Kr[j], dj, a1);
          else if ((j & 3) == 2) a2 = fma(Kr[j], dj, a2);
          else a3 = fma(Kr[j], dj, a3);
        }
        dv = (a0 + a1) + (a2 + a3);
        if (lane < 31) Dv[(k + 1) * 33 + lane] = dv;
      }
    }
    __syncthreads();

    float* __restrict__ ob = yadv_g + (size_t)b * kPred * kLat;
    if (tid < 256) {
      ob[tid] = ybuf[tid >> 3][tid & 7];  // p < 32: exact copy of y
    } else if (tid < 512) {
      const int q = tid - 256;
      const int k = q >> 3, l = q & 7;
      double a0 = 0.0, a1 = 0.0, a2 = 0.0, a3 = 0.0;
#pragma unroll
      for (int j = 0; j < 31; ++j) {
        const double t = yd[l * 65 + j + 1] ;
        if ((j & 3) == 0) a0 = fma(t, Dv[k * 33 + j], a0);
        else if ((j & 3) == 1) a1 = fma(t, Dv[k * 33 + j], a1);
        else if ((j & 3) == 2) a2 = fma(t, Dv[k * 33 + j], a2);
        else a3 = fma(t, Dv[k * 33 + j], a3);
      }
      const float v = (float)((a0 + a1) + (a2 + a3));
      ob[256 + q] = v;
      yadv2[k][l] = v;
    }
    __syncthreads();  // yd/Dv dead; frag region free for decoder
  }

  // ---- decoder input layer 8 -> 128, 96 rows (natural write) ----
  {
    const int j = tid & 127, rg = tid >> 7;  // 12 rows each
    float wr[kLat];
#pragma unroll
    for (int k = 0; k < kLat; ++k) wr[k] = dwin[k * kNN + j];
    const float bj = dbin[j];
#pragma unroll
    for (int rr = 0; rr < 12; ++rr) {
      const int r = rg * 12 + rr;
      const float* __restrict__ src = (r < kT) ? &ybuf[r][0] : &yadv2[r - kT][0];
      float a = bj;
#pragma unroll
      for (int k = 0; k < kLat; ++k) a += src[k] * wr[k];
      hb[r * kHRow + j] = fmaxf(a, 0.f);
    }
  }
  __syncthreads();

  // ---- decoder hidden layers (2-split, 3 products; terminal path) ----
#pragma unroll
  for (int L = 0; L < 3; ++L) {
    pack_frag<6, 2>(hb, frag, tid);
    __syncthreads();
    mfma_layer<3, 2>(dwh + (size_t)L * kNN * kNN, dbh + L * kNN, frag, hb, tid);
    __syncthreads();
  }

  // ---- decoder output layer 128 -> 3 ----
  for (int idx = tid; idx < kDecRows * kPhys; idx += kThreads) {
    const int r = idx / 3, o = idx - r * 3;
    float a = dbout[o];
    for (int k4 = 0; k4 < kNN; k4 += 4) {
      const float4 hv = *(const float4*)&hb[r * kHRow + k4];
      a += hv.x * dwout[(k4 + 0) * kPhys + o] + hv.y * dwout[(k4 + 1) * kPhys + o]
         + hv.z * dwout[(k4 + 2) * kPhys + o] + hv.w * dwout[(k4 + 3) * kPhys + o];
    }
    if (r < kT) {
      xae_g[(size_t)b * kT * kPhys + idx] = a;
      if (r < kWin) xadv_g[(size_t)b * kT * kPhys + idx] = a;
    } else {
      const int rr = r - kT + kWin;  // 32..63
      xadv_g[(size_t)b * kT * kPhys + rr * kPhys + o] = a;
    }
  }
}

extern "C" void kernel_launch(void* const* d_in, const int* in_sizes, int n_in,
                              void* d_out, int out_size, void* d_ws, size_t ws_size,
                              hipStream_t stream)
{
  const float* x         = (const float*)d_in[0];
  const float* enc_w_in  = (const float*)d_in[1];
  const float* enc_b_in  = (const float*)d_in[2];
  const float* enc_w_h   = (const float*)d_in[3];
  const float* enc_b_h   = (const float*)d_in[4];
  const float* enc_w_out = (const float*)d_in[5];
  const float* enc_b_out = (const float*)d_in[6];
  const float* dec_w_in  = (const float*)d_in[7];
  const float* dec_b_in  = (const float*)d_in[8];
  const float* dec_w_h   = (const float*)d_in[9];
  const float* dec_b_h   = (const float*)d_in[10];
  const float* dec_w_out = (const float*)d_in[11];
  const float* dec_b_out = (const float*)d_in[12];

  float* out   = (float*)d_out;
  float* y     = out;                                  // (B,T,8)   131072
  float* x_ae  = out + (size_t)kB * kT * kLat;         // (B,T,3)    49152
  float* x_adv = x_ae + (size_t)kB * kT * kPhys;       // (B,T,3)    49152
  float* y_adv = x_adv + (size_t)kB * kT * kPhys;      // (B,64,8)  131072

  fused_kernel<<<kB, kThreads, 0, stream>>>(
      x, enc_w_in, enc_b_in, enc_w_h, enc_b_h, enc_w_out, enc_b_out,
      dec_w_in, dec_b_in, dec_w_h, dec_b_h, dec_w_out, dec_b_out,
      y, x_ae, x_adv, y_adv);
}

// Round 6
// 57.187 us; speedup vs baseline: 5.0408x; 1.0566x over previous
//
#include <hip/hip_runtime.h>
#include <math.h>

namespace {
constexpr int kB = 256;
constexpr int kT = 64;
constexpr int kPhys = 3;
constexpr int kLat = 8;
constexpr int kNN = 128;
constexpr int kWin = 32;
constexpr int kPred = 64;
constexpr int kHRow = 132;       // padded f32 activation row
constexpr int kDecRows = 96;     // 64 (x_ae) + 32 (new y_adv rows)
constexpr int kThreads = 1024;
constexpr int kWUnit = 8 * 4 * 64 * 8;  // 16384 shorts per weight plane-unit
}

typedef short bf16x8 __attribute__((ext_vector_type(8)));
typedef float f32x4 __attribute__((ext_vector_type(4)));

__device__ __forceinline__ double rdlane_f64(double x, int l) {
  const long long v = __double_as_longlong(x);
  const int lo = __builtin_amdgcn_readlane((int)(unsigned int)(v & 0xffffffffll), l);
  const int hi = __builtin_amdgcn_readlane((int)(v >> 32), l);
  const long long r = (((long long)hi) << 32) | (unsigned long long)(unsigned int)lo;
  return __longlong_as_double(r);
}

__device__ __forceinline__ unsigned rneb(float f) {  // f32 -> bf16 bits (RNE)
  const unsigned u = __float_as_uint(f);
  return (u + 0x7fffu + ((u >> 16) & 1u)) >> 16;
}
// 3-way split: a ~= b1+b2+b3 with O(2^-25)|a| error (f32-equivalent products)
__device__ __forceinline__ void split3(float a, short& s1, short& s2, short& s3) {
  const unsigned b1 = rneb(a);
  const float f1 = __uint_as_float(b1 << 16);
  const float r1 = a - f1;
  const unsigned b2 = rneb(r1);
  const float f2 = __uint_as_float(b2 << 16);
  s1 = (short)b1; s2 = (short)b2; s3 = (short)rneb(r1 - f2);
}
// 2-way split (decoder-only; terminal outputs). Matches first two of split3.
__device__ __forceinline__ void split2(float a, short& s1, short& s2) {
  const unsigned b1 = rneb(a);
  const float f1 = __uint_as_float(b1 << 16);
  s1 = (short)b1; s2 = (short)rneb(a - f1);
}

// ---- prologue: split hidden weights into B-fragment planes (launch-invariant) ----
// unit layout: enc layer L -> units L*3+{0,1,2}; dec layer L -> units 9+L*2+{0,1}
// within unit: offset = ((n*4+q)*64 + l)*8 + e  (bf16 planes)
__global__ __launch_bounds__(256) void split_weights_kernel(
    const float* __restrict__ ewh, const float* __restrict__ dwh,
    short* __restrict__ wfrag)
{
  const int gid = blockIdx.x * 256 + threadIdx.x;  // 12288 = 6 layers x 8n x 4q x 64l
  const int l = gid & 63;
  const int q = (gid >> 6) & 3;
  const int n = (gid >> 8) & 7;
  const int layer = gid >> 11;  // 0..5
  const bool enc = layer < 3;
  const float* __restrict__ W = enc ? (ewh + (size_t)layer * kNN * kNN)
                                    : (dwh + (size_t)(layer - 3) * kNN * kNN);
  const int colg = 16 * n + (l & 15);
  const int krow = 8 * (l >> 4);
  bf16x8 p1, p2, p3;
#pragma unroll
  for (int e = 0; e < 8; ++e) {
    const float wv = W[(32 * q + krow + e) * kNN + colg];
    short s1, s2, s3; split3(wv, s1, s2, s3);
    p1[e] = s1; p2[e] = s2; p3[e] = s3;
  }
  const int off = ((n * 4 + q) * 64 + l) * 8;
  if (enc) {
    const size_t base = (size_t)(layer * 3) * kWUnit;
    *(bf16x8*)&wfrag[base + off] = p1;
    *(bf16x8*)&wfrag[base + kWUnit + off] = p2;
    *(bf16x8*)&wfrag[base + 2 * kWUnit + off] = p3;
  } else {
    const size_t base = (size_t)(9 + (layer - 3) * 2) * kWUnit;
    *(bf16x8*)&wfrag[base + off] = p1;
    *(bf16x8*)&wfrag[base + kWUnit + off] = p2;
  }
}

// ---- pack: hb (natural f32 [rows][132]) -> A-fragment planes (contiguous) ----
template<int MT, int SPLITS>
__device__ __forceinline__ void pack_frag(const float* __restrict__ hb,
                                          short* __restrict__ frag, int tid)
{
  constexpr int PLANE = MT * 4 * 64 * 8;
  for (int idx = tid; idx < MT * 256; idx += kThreads) {
    const int m = idx >> 8, q = (idx >> 6) & 3, l = idx & 63;
    const int row = 16 * m + (l & 15), col = 32 * q + 8 * (l >> 4);
    const float4 f0 = *(const float4*)&hb[row * kHRow + col];
    const float4 f1 = *(const float4*)&hb[row * kHRow + col + 4];
    const float f[8] = {f0.x, f0.y, f0.z, f0.w, f1.x, f1.y, f1.z, f1.w};
    bf16x8 p1, p2, p3;
#pragma unroll
    for (int e = 0; e < 8; ++e) {
      if constexpr (SPLITS == 3) {
        short s1, s2, s3; split3(f[e], s1, s2, s3);
        p1[e] = s1; p2[e] = s2; p3[e] = s3;
      } else {
        short s1, s2; split2(f[e], s1, s2);
        p1[e] = s1; p2[e] = s2;
      }
    }
    const int o = ((m * 4 + q) * 64 + l) * 8;
    *(bf16x8*)&frag[o] = p1;
    *(bf16x8*)&frag[PLANE + o] = p2;
    if constexpr (SPLITS == 3) *(bf16x8*)&frag[2 * PLANE + o] = p3;
  }
}

// ---- one hidden layer 128->128 (+relu) via MFMA; B from precomputed frags ----
template<int MPW, int SPLITS>
__device__ __forceinline__ void mfma_layer(
    const short* __restrict__ Bfrag, const float* __restrict__ bias,
    const short* __restrict__ frag, float* __restrict__ hb, int tid)
{
  constexpr int MT = 2 * MPW;
  constexpr int PLANE = MT * 4 * 64 * 8;
  const int w = tid >> 6, l = tid & 63;
  const int n = w & 7, m0 = (w >> 3) * MPW;
  const int colg = 16 * n + (l & 15);
  bf16x8 B1[4], B2[4], B3[4];
#pragma unroll
  for (int q = 0; q < 4; ++q) {
    const int boff = ((n * 4 + q) * 64 + l) * 8;
    B1[q] = *(const bf16x8*)&Bfrag[boff];
    B2[q] = *(const bf16x8*)&Bfrag[kWUnit + boff];
    if constexpr (SPLITS == 3) B3[q] = *(const bf16x8*)&Bfrag[2 * kWUnit + boff];
  }
  const float bj = bias[colg];
  f32x4 acc[MPW];
#pragma unroll
  for (int mi = 0; mi < MPW; ++mi) acc[mi] = {bj, bj, bj, bj};
#pragma unroll
  for (int q = 0; q < 4; ++q) {
#pragma unroll
    for (int mi = 0; mi < MPW; ++mi) {
      const int o = (((m0 + mi) * 4 + q) * 64 + l) * 8;
      const bf16x8 a1 = *(const bf16x8*)&frag[o];
      const bf16x8 a2 = *(const bf16x8*)&frag[PLANE + o];
      acc[mi] = __builtin_amdgcn_mfma_f32_16x16x32_bf16(a1, B1[q], acc[mi], 0, 0, 0);
      acc[mi] = __builtin_amdgcn_mfma_f32_16x16x32_bf16(a1, B2[q], acc[mi], 0, 0, 0);
      acc[mi] = __builtin_amdgcn_mfma_f32_16x16x32_bf16(a2, B1[q], acc[mi], 0, 0, 0);
      if constexpr (SPLITS == 3) {
        const bf16x8 a3 = *(const bf16x8*)&frag[2 * PLANE + o];
        acc[mi] = __builtin_amdgcn_mfma_f32_16x16x32_bf16(a1, B3[q], acc[mi], 0, 0, 0);
        acc[mi] = __builtin_amdgcn_mfma_f32_16x16x32_bf16(a2, B2[q], acc[mi], 0, 0, 0);
        acc[mi] = __builtin_amdgcn_mfma_f32_16x16x32_bf16(a3, B1[q], acc[mi], 0, 0, 0);
      }
    }
  }
  const int rbase = (l >> 4) * 4;
#pragma unroll
  for (int mi = 0; mi < MPW; ++mi)
#pragma unroll
    for (int r = 0; r < 4; ++r)
      hb[(16 * (m0 + mi) + rbase + r) * kHRow + colg] = fmaxf(acc[mi][r], 0.f);
}

__global__ __launch_bounds__(kThreads, 4) void fused_kernel(
    const float* __restrict__ x,
    const float* __restrict__ ewin, const float* __restrict__ ebin,
    const float* __restrict__ ebh,
    const float* __restrict__ ewout,const float* __restrict__ ebout,
    const float* __restrict__ dwin, const float* __restrict__ dbin,
    const float* __restrict__ dbh,
    const float* __restrict__ dwout,const float* __restrict__ dbout,
    const short* __restrict__ wfrag,
    float* __restrict__ y_g, float* __restrict__ xae_g,
    float* __restrict__ xadv_g, float* __restrict__ yadv_g)
{
  __shared__ float hb[kDecRows * kHRow];            // 50688 B, natural activations
  __shared__ __align__(16) char fragbuf[49152];     // frag planes / DMD f64 scratch
  __shared__ float ybuf[kT][kLat + 1];
  __shared__ float yadv2[kWin][kLat + 1];
  __shared__ float inb[kT][4];

  short* frag = (short*)fragbuf;
  double* dmd = (double*)fragbuf;
  double* yd   = dmd;           // [8][65]
  double* P    = dmd + 520;     // [32][67]
  double* Corr = dmd + 2664;    // [32][33]
  double* KTm  = dmd + 3720;    // [31][33]
  double* Dv   = dmd + 4743;    // [32][33]

  const int tid = threadIdx.x;
  const int b = blockIdx.x;

  // ---- load x ----
  const float* __restrict__ xg = x + (size_t)b * kT * kPhys;
  for (int i = tid; i < kT * kPhys; i += kThreads) inb[i / 3][i % 3] = xg[i];
  __syncthreads();

  // ---- encoder input layer 3 -> 128 (natural write) ----
  {
    const int j = tid & 127, rg = tid >> 7;  // rg 0..7, 8 rows each
    const float w0 = ewin[j], w1 = ewin[kNN + j], w2 = ewin[2 * kNN + j];
    const float bj = ebin[j];
#pragma unroll
    for (int rr = 0; rr < 8; ++rr) {
      const int r = rg * 8 + rr;
      hb[r * kHRow + j] = fmaxf(bj + inb[r][0] * w0 + inb[r][1] * w1 + inb[r][2] * w2, 0.f);
    }
  }
  __syncthreads();

  // ---- encoder hidden layers (3-split, f32-exact) ----
#pragma unroll
  for (int L = 0; L < 3; ++L) {
    pack_frag<4, 3>(hb, frag, tid);
    __syncthreads();
    mfma_layer<2, 3>(wfrag + (size_t)(L * 3) * kWUnit, ebh + L * kNN, frag, hb, tid);
    __syncthreads();
  }

  // ---- encoder output layer 128 -> 8 (also fills yd for DMD) ----
  if (tid < 512) {
    const int r = tid >> 3, o = tid & 7;
    float a = ebout[o];
    for (int k4 = 0; k4 < kNN; k4 += 4) {
      const float4 hv = *(const float4*)&hb[r * kHRow + k4];
      a += hv.x * ewout[(k4 + 0) * kLat + o] + hv.y * ewout[(k4 + 1) * kLat + o]
         + hv.z * ewout[(k4 + 2) * kLat + o] + hv.w * ewout[(k4 + 3) * kLat + o];
    }
    ybuf[r][o] = a;
    y_g[(size_t)b * kT * kLat + tid] = a;
    yd[o * 65 + r] = (double)a;  // frag region free (last mfma consumed it)
  }
  __syncthreads();

  // ---- Hankel-DMD (f64, exact-math rewrite) ----
  {
    for (int idx = tid; idx < 32 * 64; idx += kThreads) {
      const int d = idx >> 6, t = idx & 63;
      if (t + d < kT) {
        double s = 0.0;
#pragma unroll
        for (int l = 0; l < kLat; ++l) s += yd[l * 65 + t] * yd[l * 65 + t + d];
        P[d * 67 + t] = s;
      }
    }
    __syncthreads();

    {
      const int a = tid >> 5, c = tid & 31;
      const int d = (c >= a) ? (c - a) : (a - c);
      const int base = (c >= a) ? a : c;
      double s0 = 0.0, s1 = 0.0;
#pragma unroll
      for (int r = 0; r < 32; r += 2) { s0 += P[d * 67 + base + r]; s1 += P[d * 67 + base + r + 1]; }
      Corr[a * 33 + c] = s0 + s1 + P[d * 67 + base + 32];
    }
    __syncthreads();

    // single-wave register Gauss-Jordan [G|C] -> [I|K], then power iteration
    if (tid < 64) {
      const int lane = tid;
      const int colidx = (lane <= 30) ? lane : (lane <= 61 ? lane - 30 : 1);
      double m[31];
#pragma unroll
      for (int i = 0; i < 31; ++i) m[i] = Corr[i * 33 + colidx];
#pragma unroll
      for (int k = 0; k < 31; ++k) {
        const double piv = rdlane_f64(m[k], k);
        const double pinv = 1.0 / piv;
        m[k] *= pinv;
#pragma unroll
        for (int i = 0; i < 31; ++i) {
          if (i == k) continue;
          const double bci = rdlane_f64(m[i], k);
          m[i] = fma(-bci, m[k], m[i]);
        }
      }
      if (lane >= 31 && lane < 62) {
        const int c = lane - 31;
#pragma unroll
        for (int i = 0; i < 31; ++i) KTm[i * 33 + c] = m[i];
      }
      const int ri = (lane < 31) ? lane : 0;
      double Kr[31];
#pragma unroll
      for (int j = 0; j < 31; ++j) Kr[j] = KTm[ri * 33 + j];

      double dv = Kr[30];  // d_0 = K[:,30]
      if (lane < 31) Dv[0 * 33 + lane] = dv;
      for (int k = 0; k < 31; ++k) {
        double a0 = 0.0, a1 = 0.0, a2 = 0.0, a3 = 0.0;
#pragma unroll
        for (int j = 0; j < 31; ++j) {
          const double dj = rdlane_f64(dv, j);
          if ((j & 3) == 0) a0 = fma(Kr[j], dj, a0);
          else if ((j & 3) == 1) a1 = fma(Kr[j], dj, a1);
          else if ((j & 3) == 2) a2 = fma(Kr[j], dj, a2);
          else a3 = fma(Kr[j], dj, a3);
        }
        dv = (a0 + a1) + (a2 + a3);
        if (lane < 31) Dv[(k + 1) * 33 + lane] = dv;
      }
    }
    __syncthreads();

    float* __restrict__ ob = yadv_g + (size_t)b * kPred * kLat;
    if (tid < 256) {
      ob[tid] = ybuf[tid >> 3][tid & 7];  // p < 32: exact copy of y
    } else if (tid < 512) {
      const int q = tid - 256;
      const int k = q >> 3, l = q & 7;
      double a0 = 0.0, a1 = 0.0, a2 = 0.0, a3 = 0.0;
#pragma unroll
      for (int j = 0; j < 31; ++j) {
        const double t = yd[l * 65 + j + 1];
        if ((j & 3) == 0) a0 = fma(t, Dv[k * 33 + j], a0);
        else if ((j & 3) == 1) a1 = fma(t, Dv[k * 33 + j], a1);
        else if ((j & 3) == 2) a2 = fma(t, Dv[k * 33 + j], a2);
        else a3 = fma(t, Dv[k * 33 + j], a3);
      }
      const float v = (float)((a0 + a1) + (a2 + a3));
      ob[256 + q] = v;
      yadv2[k][l] = v;
    }
    __syncthreads();  // yd/Dv dead; frag region free for decoder
  }

  // ---- decoder input layer 8 -> 128, 96 rows (natural write) ----
  {
    const int j = tid & 127, rg = tid >> 7;  // 12 rows each
    float wr[kLat];
#pragma unroll
    for (int k = 0; k < kLat; ++k) wr[k] = dwin[k * kNN + j];
    const float bj = dbin[j];
#pragma unroll
    for (int rr = 0; rr < 12; ++rr) {
      const int r = rg * 12 + rr;
      const float* __restrict__ src = (r < kT) ? &ybuf[r][0] : &yadv2[r - kT][0];
      float a = bj;
#pragma unroll
      for (int k = 0; k < kLat; ++k) a += src[k] * wr[k];
      hb[r * kHRow + j] = fmaxf(a, 0.f);
    }
  }
  __syncthreads();

  // ---- decoder hidden layers (2-split, 3 products; terminal path) ----
#pragma unroll
  for (int L = 0; L < 3; ++L) {
    pack_frag<6, 2>(hb, frag, tid);
    __syncthreads();
    mfma_layer<3, 2>(wfrag + (size_t)(9 + L * 2) * kWUnit, dbh + L * kNN, frag, hb, tid);
    __syncthreads();
  }

  // ---- decoder output layer 128 -> 3 ----
  for (int idx = tid; idx < kDecRows * kPhys; idx += kThreads) {
    const int r = idx / 3, o = idx - r * 3;
    float a = dbout[o];
    for (int k4 = 0; k4 < kNN; k4 += 4) {
      const float4 hv = *(const float4*)&hb[r * kHRow + k4];
      a += hv.x * dwout[(k4 + 0) * kPhys + o] + hv.y * dwout[(k4 + 1) * kPhys + o]
         + hv.z * dwout[(k4 + 2) * kPhys + o] + hv.w * dwout[(k4 + 3) * kPhys + o];
    }
    if (r < kT) {
      xae_g[(size_t)b * kT * kPhys + idx] = a;
      if (r < kWin) xadv_g[(size_t)b * kT * kPhys + idx] = a;
    } else {
      const int rr = r - kT + kWin;  // 32..63
      xadv_g[(size_t)b * kT * kPhys + rr * kPhys + o] = a;
    }
  }
}

extern "C" void kernel_launch(void* const* d_in, const int* in_sizes, int n_in,
                              void* d_out, int out_size, void* d_ws, size_t ws_size,
                              hipStream_t stream)
{
  const float* x         = (const float*)d_in[0];
  const float* enc_w_in  = (const float*)d_in[1];
  const float* enc_b_in  = (const float*)d_in[2];
  const float* enc_w_h   = (const float*)d_in[3];
  const float* enc_b_h   = (const float*)d_in[4];
  const float* enc_w_out = (const float*)d_in[5];
  const float* enc_b_out = (const float*)d_in[6];
  const float* dec_w_in  = (const float*)d_in[7];
  const float* dec_b_in  = (const float*)d_in[8];
  const float* dec_w_h   = (const float*)d_in[9];
  const float* dec_b_h   = (const float*)d_in[10];
  const float* dec_w_out = (const float*)d_in[11];
  const float* dec_b_out = (const float*)d_in[12];

  float* out   = (float*)d_out;
  float* y     = out;                                  // (B,T,8)   131072
  float* x_ae  = out + (size_t)kB * kT * kLat;         // (B,T,3)    49152
  float* x_adv = x_ae + (size_t)kB * kT * kPhys;       // (B,T,3)    49152
  float* y_adv = x_adv + (size_t)kB * kT * kPhys;      // (B,64,8)  131072

  short* wfrag = (short*)d_ws;   // 15 units x 16384 shorts = 491520 B

  split_weights_kernel<<<48, 256, 0, stream>>>(enc_w_h, dec_w_h, wfrag);
  fused_kernel<<<kB, kThreads, 0, stream>>>(
      x, enc_w_in, enc_b_in, enc_b_h, enc_w_out, enc_b_out,
      dec_w_in, dec_b_in, dec_b_h, dec_w_out, dec_b_out,
      wfrag, y, x_ae, x_adv, y_adv);
}